// Round 13
// baseline (47.021 us; speedup 1.0000x reference)
//
#include <hip/hip_runtime.h>
#include <hip/hip_bf16.h>
#include <stdint.h>

typedef __attribute__((ext_vector_type(8))) short bf16x8;
typedef __attribute__((ext_vector_type(16))) float f32x16;
using bf16 = __hip_bfloat16;

static constexpr int Mdim = 512;   // A batch
static constexpr int Ndim = 64;    // B batch
static constexpr int Cdim = 128;   // channels (K of the GEMM)
static constexpr int Pdim = 64;    // H*W positions
static constexpr float EPS_ADD = 0.001f;

#define SB0 __builtin_amdgcn_sched_barrier(0)
#define WAITV(N) asm volatile("s_waitcnt vmcnt(" #N ")" ::: "memory")

// ---------------------------------------------------------------------------
// async global->LDS, 16B per lane
// ---------------------------------------------------------------------------
__device__ __forceinline__ void gll16(const void* gsrc, void* ldst) {
    const __attribute__((address_space(1))) unsigned int* g =
        (const __attribute__((address_space(1))) unsigned int*)gsrc;
    __attribute__((address_space(3))) unsigned int* l =
        (__attribute__((address_space(3))) unsigned int*)(uintptr_t)ldst;
    __builtin_amdgcn_global_load_lds(g, l, 16, 0, 0);
}

// ---------------------------------------------------------------------------
// prep (fused, UNCHANGED — verified): fragment-ordered outputs.
//   A-tile (per m): idx = h*4096 + ks*512 + lane*8 + e
//     p = h*32 + (lane&31), c = ks*16 + (lane>>5)*8 + e
//   G-tile (per n): idx = qt*4096 + ks*512 + lane*8 + e
//     q = qt*32 + (lane&31), c = ks*16 + (lane>>5)*8 + e
// ---------------------------------------------------------------------------
__global__ void prep_kernel(const float* __restrict__ A, const float* __restrict__ B,
                            const float* __restrict__ Wg,
                            bf16* __restrict__ Afrag, bf16* __restrict__ Gfrag) {
    __shared__ float lds[128 * 65];
    const int t = threadIdx.x;

    if (blockIdx.x < 512) {
        const int m = blockIdx.x;
        const float* __restrict__ Am = A + (size_t)m * (Cdim * Pdim);
#pragma unroll
        for (int i = 0; i < 8; ++i) {
            int v = t + i * 256;
            int gidx = v * 4;
            int c = gidx >> 6, p = gidx & 63;
            float4 val = *reinterpret_cast<const float4*>(Am + gidx);
            float* dst = &lds[c * 65 + p];
            dst[0] = val.x; dst[1] = val.y; dst[2] = val.z; dst[3] = val.w;
        }
        __syncthreads();

        unsigned* __restrict__ dst32 = (unsigned*)(Afrag + (size_t)m * 8192);
#pragma unroll
        for (int i = 0; i < 16; ++i) {
            int pr = t + i * 256;
            int p = pr >> 6;
            int c = (pr & 63) << 1;
            float f0 = lds[c * 65 + p];
            float f1 = lds[(c + 1) * 65 + p];
            union { bf16 hh[2]; unsigned u; } pk;
            pk.hh[0] = __float2bfloat16(f0);
            pk.hh[1] = __float2bfloat16(f1);
            int h = p >> 5, l31 = p & 31;
            int ks = c >> 4, hi = (c >> 3) & 1, e = c & 7;
            dst32[h * 2048 + ks * 256 + hi * 128 + l31 * 4 + (e >> 1)] = pk.u;
        }
    } else {
        const int nb = blockIdx.x - 512;
        const int n  = nb >> 2;
        const int q0 = (nb & 3) * 16;
        const float* __restrict__ Bn = B + (size_t)n * (Cdim * Pdim);
#pragma unroll
        for (int i = 0; i < 8; ++i) {
            int v = t + i * 256;
            int gidx = v * 4;
            int c = gidx >> 6, q = gidx & 63;
            float4 val = *reinterpret_cast<const float4*>(Bn + gidx);
            float* dst = &lds[c * 65 + q];
            dst[0] = val.x; dst[1] = val.y; dst[2] = val.z; dst[3] = val.w;
        }
        __syncthreads();

        const int d  = t & 127;
        const int qb = q0 + (t >> 7) * 8;
        float acc[8] = {0.f, 0.f, 0.f, 0.f, 0.f, 0.f, 0.f, 0.f};
        for (int c = 0; c < 128; ++c) {
            float w = Wg[c * 128 + d];
#pragma unroll
            for (int qi = 0; qi < 8; ++qi)
                acc[qi] = fmaf(lds[c * 65 + qb + qi], w, acc[qi]);
        }
        bf16* __restrict__ gdst = Gfrag + (size_t)n * 8192;
        const int ks = d >> 4, hi = (d >> 3) & 1, e = d & 7;
#pragma unroll
        for (int qi = 0; qi < 8; ++qi) {
            int q = qb + qi;
            int qt = q >> 5, l31 = q & 31;
            gdst[qt * 4096 + ks * 512 + hi * 256 + l31 * 8 + e] = __float2bfloat16(acc[qi]);
        }
    }
}

// ---------------------------------------------------------------------------
// gemm_max v11: v10 (A-resident regs + LDS-broadcast G) with
//  (1) DISTANCE-2 G prefetch through 4 rolling LDS buffers (64KB): stage(s+2)
//      issued at step s, drained at step s+2 -> ~2 full steps (~4100 cyc) of
//      latency cover; steady-state WAITV is a no-op.
//      Safety: stage(s+2) writes the buffer last read at step s-2, whose
//      readers all passed the step-s barrier.
//  (2) s_setprio(1) around the MFMA cluster (T5; 2 independent blocks/CU
//      give the role diversity that makes it pay).
// vmcnt ledger (per thread order: A(16),s0,s1 | step s: stage(s+2)(4),
// stores(s)(2)): entry of step s in-flight = stage(s),stores(s-2),
// stage(s+1),stores(s-1) = 12 -> WAITV(8) drains exactly stage(s).
// Specials: step0 = WAITV(4) (A+s0 drained, leave s1); step1 = WAITV(6);
// step14 (no stage(16)) = WAITV(8); step15 = WAITV(4).
// Grid 512 = 128 mg x 4 bn -> exactly 2 blocks/CU, independent domains.
// ---------------------------------------------------------------------------
__global__ __launch_bounds__(256, 2)
void gemm_max_kernel(const bf16* __restrict__ Afrag, const bf16* __restrict__ Gfrag,
                     float* __restrict__ out) {
    __shared__ bf16 sG[4][8192];          // 4 x 16KB rolling, fragment order
    const int tid  = threadIdx.x;
    const int lane = tid & 63;
    const int wv   = tid >> 6;            // 0..3 -> m = mg*4 + wv
    const int l31 = lane & 31, hi = lane >> 5;
    const int mg = blockIdx.x & 127;      // 128 m-groups of 4
    const int bn = blockIdx.x >> 7;       // 4 n-groups of 16
    const int m  = mg * 4 + wv;

    // ---- A-tile resident: 16 coalesced 1KB loads (oldest vmcnt events) ----
    bf16x8 a[2][8];                       // [p-half h][ks]
    {
        const bf16* Ap = Afrag + (size_t)m * 8192 + lane * 8;
#pragma unroll
        for (int h = 0; h < 2; ++h)
#pragma unroll
            for (int ks = 0; ks < 8; ++ks)
                a[h][ks] = *reinterpret_cast<const bf16x8*>(Ap + h * 4096 + ks * 512);
    }
    asm volatile("" ::: "memory");        // pin A-loads before stage issues

    const char* Gsrc = (const char*)(Gfrag + (size_t)(bn * 16) * 8192);
    auto stageG = [&](int s) {            // 16KB: 4 x gll16 per thread
        char* dst = (char*)&sG[s & 3][0];
        const char* src = Gsrc + (size_t)s * 16384;
#pragma unroll
        for (int i = 0; i < 4; ++i) {
            int f = (i * 256 + tid) * 16;
            gll16(src + f, dst + f);
        }
    };
    stageG(0);
    stageG(1);

    f32x16 acc[2][2];                     // [qt][h]
    const f32x16 z16 = {0.f,0.f,0.f,0.f,0.f,0.f,0.f,0.f,0.f,0.f,0.f,0.f,0.f,0.f,0.f,0.f};

    auto compute = [&](int s) {
        const char* gb = (const char*)&sG[s & 3][0] + lane * 16;
        bf16x8 gf[2][8];                  // contiguous 1KB ds_read_b128 x16
#pragma unroll
        for (int qt = 0; qt < 2; ++qt)
#pragma unroll
            for (int ks = 0; ks < 8; ++ks)
                gf[qt][ks] = *reinterpret_cast<const bf16x8*>(gb + qt * 8192 + ks * 1024);
        __builtin_amdgcn_s_setprio(1);
#pragma unroll
        for (int ks = 0; ks < 8; ++ks)
#pragma unroll
            for (int qt = 0; qt < 2; ++qt)
#pragma unroll
                for (int h = 0; h < 2; ++h)
                    acc[qt][h] = __builtin_amdgcn_mfma_f32_32x32x16_bf16(
                        gf[qt][ks], a[h][ks], ks == 0 ? z16 : acc[qt][h], 0, 0, 0);
        __builtin_amdgcn_s_setprio(0);
    };

    auto epilogue = [&](int s) {
        const int ng = bn * 16 + s;
#pragma unroll
        for (int h = 0; h < 2; ++h) {
            float v = fmaxf(acc[0][h][0], acc[0][h][1]);
#pragma unroll
            for (int j = 2; j < 16; ++j) v = fmaxf(v, acc[0][h][j]);
#pragma unroll
            for (int j = 0; j < 16; ++j) v = fmaxf(v, acc[1][h][j]);
            v = fmaxf(v, __shfl_xor(v, 32));   // fold q hi-halves
            if (hi == 0)
                out[(size_t)m * 4096 + ng * 64 + h * 32 + l31] = fmaxf(v, 0.f) + EPS_ADD;
        }
    };

    // ---- step 0: drain A + stage0 (leave stage1) ----
    WAITV(4); __builtin_amdgcn_s_barrier(); SB0;
    stageG(2); compute(0); epilogue(0); SB0;

    // ---- step 1 ----
    WAITV(6); __builtin_amdgcn_s_barrier(); SB0;
    stageG(3); compute(1); epilogue(1); SB0;

    // ---- steps 2..13: steady WAITV(8) ----
    for (int s = 2; s <= 13; ++s) {
        WAITV(8); __builtin_amdgcn_s_barrier(); SB0;
        stageG(s + 2); compute(s); epilogue(s); SB0;
    }

    // ---- step 14 (no stage issued) ----
    WAITV(8); __builtin_amdgcn_s_barrier(); SB0;
    compute(14); epilogue(14); SB0;

    // ---- step 15 ----
    WAITV(4); __builtin_amdgcn_s_barrier(); SB0;
    compute(15); epilogue(15);
}

// ---------------------------------------------------------------------------
extern "C" void kernel_launch(void* const* d_in, const int* in_sizes, int n_in,
                              void* d_out, int out_size, void* d_ws, size_t ws_size,
                              hipStream_t stream) {
    const float* A  = (const float*)d_in[0];
    const float* B  = (const float*)d_in[1];
    const float* Wg = (const float*)d_in[2];
    float* out = (float*)d_out;

    bf16* Afrag = (bf16*)d_ws;                                      // 512 x 8192 bf16 = 8 MiB
    bf16* Gfrag = (bf16*)((char*)d_ws + (size_t)Mdim * Pdim * Cdim * sizeof(bf16)); // 64 x 8192 bf16

    prep_kernel<<<768, 256, 0, stream>>>(A, B, Wg, Afrag, Gfrag);
    gemm_max_kernel<<<512, 256, 0, stream>>>(Afrag, Gfrag, out);   // 128 mg x 4 bn
}

// Round 15
// 45.701 us; speedup vs baseline: 1.0289x; 1.0289x over previous
//
#include <hip/hip_runtime.h>
#include <hip/hip_bf16.h>
#include <stdint.h>

typedef __attribute__((ext_vector_type(8))) short bf16x8;
typedef __attribute__((ext_vector_type(16))) float f32x16;
using bf16 = __hip_bfloat16;

static constexpr int Mdim = 512;   // A batch
static constexpr int Ndim = 64;    // B batch
static constexpr int Cdim = 128;   // channels (K of the GEMM)
static constexpr int Pdim = 64;    // H*W positions
static constexpr float EPS_ADD = 0.001f;

#define SB0 __builtin_amdgcn_sched_barrier(0)
#define WAITV(N) asm volatile("s_waitcnt vmcnt(" #N ")" ::: "memory")

// ---------------------------------------------------------------------------
// async global->LDS, 16B per lane
// ---------------------------------------------------------------------------
__device__ __forceinline__ void gll16(const void* gsrc, void* ldst) {
    const __attribute__((address_space(1))) unsigned int* g =
        (const __attribute__((address_space(1))) unsigned int*)gsrc;
    __attribute__((address_space(3))) unsigned int* l =
        (__attribute__((address_space(3))) unsigned int*)(uintptr_t)ldst;
    __builtin_amdgcn_global_load_lds(g, l, 16, 0, 0);
}

// ---------------------------------------------------------------------------
// prep (fused, UNCHANGED — verified): fragment-ordered outputs.
//   A-tile (per m): idx = h*4096 + ks*512 + lane*8 + e
//     p = h*32 + (lane&31), c = ks*16 + (lane>>5)*8 + e
//   G-tile (per n): idx = qt*4096 + ks*512 + lane*8 + e
//     q = qt*32 + (lane&31), c = ks*16 + (lane>>5)*8 + e
// ---------------------------------------------------------------------------
__global__ void prep_kernel(const float* __restrict__ A, const float* __restrict__ B,
                            const float* __restrict__ Wg,
                            bf16* __restrict__ Afrag, bf16* __restrict__ Gfrag) {
    __shared__ float lds[128 * 65];
    const int t = threadIdx.x;

    if (blockIdx.x < 512) {
        const int m = blockIdx.x;
        const float* __restrict__ Am = A + (size_t)m * (Cdim * Pdim);
#pragma unroll
        for (int i = 0; i < 8; ++i) {
            int v = t + i * 256;
            int gidx = v * 4;
            int c = gidx >> 6, p = gidx & 63;
            float4 val = *reinterpret_cast<const float4*>(Am + gidx);
            float* dst = &lds[c * 65 + p];
            dst[0] = val.x; dst[1] = val.y; dst[2] = val.z; dst[3] = val.w;
        }
        __syncthreads();

        unsigned* __restrict__ dst32 = (unsigned*)(Afrag + (size_t)m * 8192);
#pragma unroll
        for (int i = 0; i < 16; ++i) {
            int pr = t + i * 256;
            int p = pr >> 6;
            int c = (pr & 63) << 1;
            float f0 = lds[c * 65 + p];
            float f1 = lds[(c + 1) * 65 + p];
            union { bf16 hh[2]; unsigned u; } pk;
            pk.hh[0] = __float2bfloat16(f0);
            pk.hh[1] = __float2bfloat16(f1);
            int h = p >> 5, l31 = p & 31;
            int ks = c >> 4, hi = (c >> 3) & 1, e = c & 7;
            dst32[h * 2048 + ks * 256 + hi * 128 + l31 * 4 + (e >> 1)] = pk.u;
        }
    } else {
        const int nb = blockIdx.x - 512;
        const int n  = nb >> 2;
        const int q0 = (nb & 3) * 16;
        const float* __restrict__ Bn = B + (size_t)n * (Cdim * Pdim);
#pragma unroll
        for (int i = 0; i < 8; ++i) {
            int v = t + i * 256;
            int gidx = v * 4;
            int c = gidx >> 6, q = gidx & 63;
            float4 val = *reinterpret_cast<const float4*>(Bn + gidx);
            float* dst = &lds[c * 65 + q];
            dst[0] = val.x; dst[1] = val.y; dst[2] = val.z; dst[3] = val.w;
        }
        __syncthreads();

        const int d  = t & 127;
        const int qb = q0 + (t >> 7) * 8;
        float acc[8] = {0.f, 0.f, 0.f, 0.f, 0.f, 0.f, 0.f, 0.f};
        for (int c = 0; c < 128; ++c) {
            float w = Wg[c * 128 + d];
#pragma unroll
            for (int qi = 0; qi < 8; ++qi)
                acc[qi] = fmaf(lds[c * 65 + qb + qi], w, acc[qi]);
        }
        bf16* __restrict__ gdst = Gfrag + (size_t)n * 8192;
        const int ks = d >> 4, hi = (d >> 3) & 1, e = d & 7;
#pragma unroll
        for (int qi = 0; qi < 8; ++qi) {
            int q = qb + qi;
            int qt = q >> 5, l31 = q & 31;
            gdst[qt * 4096 + ks * 512 + hi * 256 + l31 * 8 + e] = __float2bfloat16(acc[qi]);
        }
    }
}

// ---------------------------------------------------------------------------
// gemm_max v12: R=2 register reuse — wave = 2 m's x one p-half.
//  - Each ds_read G-fragment feeds 2 MFMA -> 512 B LDS per MFMA (half of
//    v10/v11), putting the LDS pipe well under the MFMA pipe per CU-step.
//  - Online max over qt: acc[2] (2x16 regs) reused across qt phases; running
//    scalar r[2] -> live VGPR ~140 -> __launch_bounds__(256,3): 3 blocks/CU
//    (3 independent barrier domains to absorb join skew).
//  - G: 16KB/step through 3 rolling LDS bufs (48KB), dist-2 prefetch issued
//    right after the barrier. Safety: stage(s+2) writes buf (s-1)%3 whose
//    readers passed the step-s barrier.
//  - Block = 4 waves (mi,h) = 4 m's x full p; 8 n-steps (n = bn*8+s).
// vmcnt ledger (per-step order: stage(s+2)(4) ... stores(s)(2)):
//   entry of step s: stage(s),stores(s-2),stage(s+1),stores(s-1) = 12
//   -> WAITV(8) drains stage(s). Step0: W(4) (A(16)+s0 drained, leave s1);
//   step1: W(6); steps 2..6: W(8); step7: W(4).
// Grid 1024 = 8 bn x 128 mg, bid = bn*128+mg -> bid%8 = mg%8 (XCD locality).
// MFMA 32x32x16, mfma(G, A, acc): D col = lane&31 = p, row = q (m74/m101).
// ---------------------------------------------------------------------------
__global__ __launch_bounds__(256, 3)
void gemm_max_kernel(const bf16* __restrict__ Afrag, const bf16* __restrict__ Gfrag,
                     float* __restrict__ out) {
    __shared__ bf16 sG[3][8192];          // 3 x 16KB rolling, fragment order
    const int tid  = threadIdx.x;
    const int lane = tid & 63;
    const int wv   = tid >> 6;            // 0..3
    const int mi = wv >> 1, h = wv & 1;   // wave: m-pair index, p-half
    const int l31 = lane & 31, hi = lane >> 5;
    const int mg = blockIdx.x & 127;      // 128 m-groups of 4
    const int bn = blockIdx.x >> 7;       // 8 n-groups of 8
    const int m0 = mg * 4 + mi * 2;       // wave handles m0, m0+1

    // ---- A resident: 16 coalesced 1KB loads (oldest vmcnt events) ----
    bf16x8 a[2][8];                       // [m-sub][ks]
    {
#pragma unroll
        for (int u = 0; u < 2; ++u) {
            const bf16* Ap = Afrag + (size_t)(m0 + u) * 8192 + h * 4096 + lane * 8;
#pragma unroll
            for (int ks = 0; ks < 8; ++ks)
                a[u][ks] = *reinterpret_cast<const bf16x8*>(Ap + ks * 512);
        }
    }
    asm volatile("" ::: "memory");        // pin A-loads before stage issues

    const char* Gsrc = (const char*)(Gfrag + (size_t)(bn * 8) * 8192);
    auto stageG = [&](int s) {            // 16KB: 4 x gll16 per thread
        char* dst = (char*)&sG[s % 3][0];
        const char* src = Gsrc + (size_t)s * 16384;
#pragma unroll
        for (int i = 0; i < 4; ++i) {
            int f = (i * 256 + tid) * 16;
            gll16(src + f, dst + f);
        }
    };
    stageG(0);
    stageG(1);

    const f32x16 z16 = {0.f,0.f,0.f,0.f,0.f,0.f,0.f,0.f,0.f,0.f,0.f,0.f,0.f,0.f,0.f,0.f};

    auto step = [&](int s) {
        const char* gb = (const char*)&sG[s % 3][0] + lane * 16;
        float r0, r1;
#pragma unroll
        for (int qt = 0; qt < 2; ++qt) {
            f32x16 acc0, acc1;            // reused across qt (online max)
            __builtin_amdgcn_s_setprio(1);
#pragma unroll
            for (int ks = 0; ks < 8; ++ks) {
                bf16x8 gf = *reinterpret_cast<const bf16x8*>(gb + qt * 8192 + ks * 1024);
                acc0 = __builtin_amdgcn_mfma_f32_32x32x16_bf16(
                    gf, a[0][ks], ks == 0 ? z16 : acc0, 0, 0, 0);
                acc1 = __builtin_amdgcn_mfma_f32_32x32x16_bf16(
                    gf, a[1][ks], ks == 0 ? z16 : acc1, 0, 0, 0);
            }
            __builtin_amdgcn_s_setprio(0);
            // in-lane reduce 16 -> 1 per m-sub (pairwise -> v_max3-friendly)
            float t0 = fmaxf(acc0[0], acc0[1]);
#pragma unroll
            for (int j = 2; j < 16; ++j) t0 = fmaxf(t0, acc0[j]);
            float t1 = fmaxf(acc1[0], acc1[1]);
#pragma unroll
            for (int j = 2; j < 16; ++j) t1 = fmaxf(t1, acc1[j]);
            if (qt == 0) { r0 = t0; r1 = t1; }
            else         { r0 = fmaxf(r0, t0); r1 = fmaxf(r1, t1); }
        }
        // fold q hi-halves, relu+eps, store (hi==0 lanes)
        r0 = fmaxf(r0, __shfl_xor(r0, 32));
        r1 = fmaxf(r1, __shfl_xor(r1, 32));
        const int n = bn * 8 + s;
        if (hi == 0) {
            out[(size_t)m0 * 4096 + n * 64 + h * 32 + l31]       = fmaxf(r0, 0.f) + EPS_ADD;
            out[(size_t)(m0 + 1) * 4096 + n * 64 + h * 32 + l31] = fmaxf(r1, 0.f) + EPS_ADD;
        }
    };

    // ---- step 0: drain A + stage0 (leave stage1) ----
    WAITV(4); __builtin_amdgcn_s_barrier(); SB0;
    stageG(2); step(0); SB0;

    // ---- step 1 ----
    WAITV(6); __builtin_amdgcn_s_barrier(); SB0;
    stageG(3); step(1); SB0;

    // ---- steps 2..5: steady WAITV(8), dist-2 prefetch ----
    for (int s = 2; s <= 5; ++s) {
        WAITV(8); __builtin_amdgcn_s_barrier(); SB0;
        stageG(s + 2); step(s); SB0;
    }

    // ---- step 6 (no stage issued) ----
    WAITV(8); __builtin_amdgcn_s_barrier(); SB0;
    step(6); SB0;

    // ---- step 7 ----
    WAITV(4); __builtin_amdgcn_s_barrier(); SB0;
    step(7);
}

// ---------------------------------------------------------------------------
extern "C" void kernel_launch(void* const* d_in, const int* in_sizes, int n_in,
                              void* d_out, int out_size, void* d_ws, size_t ws_size,
                              hipStream_t stream) {
    const float* A  = (const float*)d_in[0];
    const float* B  = (const float*)d_in[1];
    const float* Wg = (const float*)d_in[2];
    float* out = (float*)d_out;

    bf16* Afrag = (bf16*)d_ws;                                      // 512 x 8192 bf16 = 8 MiB
    bf16* Gfrag = (bf16*)((char*)d_ws + (size_t)Mdim * Pdim * Cdim * sizeof(bf16)); // 64 x 8192 bf16

    prep_kernel<<<768, 256, 0, stream>>>(A, B, Wg, Afrag, Gfrag);
    gemm_max_kernel<<<1024, 256, 0, stream>>>(Afrag, Gfrag, out);   // 8 bn x 128 mg
}